// Round 6
// baseline (92.735 us; speedup 1.0000x reference)
//
#include <hip/hip_runtime.h>

// Multivariate Hawkes log-likelihood, N=8192, D=10.
// Pair term: ab*exp(-b*(ti-tj)) = exp2(P*ti + L), P = -b*log2e (per (e_i,e_j)),
// L = log2(a*b) - P*t_j. Per j-chunk we precompute (P,L) for all 10 e_i rows,
// packed 2 pairs per float4 -> one ds_read_b128 per 2 pairs in the hot loop.
//
// Occupancy fix vs prior round: j-chunks of 128 (grid 64x32, 1056 active
// blocks ~ 4/CU ~ 4 waves/SIMD) and float4 LDS reads (half the LDS ops).
// Row stride 65 float4 = 260 words (260 mod 32 = 4): rows map to distinct
// bank quads except {0,8},{1,9} -> worst 2-way conflict (free).
//
//   hawkes_pairs : block (ib,jb), jb<=2*ib+1; writes 256 partial sums to
//                  partial[jb*8192+i] (single writer, poison-safe).
//                  Block (0,0) zeroes out[0] (same-stream order protects it).
//   hawkes_finish: 32 blocks x 256 thr; log-intensity minus integral tail,
//                  block reduce, atomicAdd into out[0].

#define N_EV 8192
#define DT 10
#define LOG2E 1.4426950408889634f
#define JCH 128
#define R4 65   // row stride in float4 units

__device__ __forceinline__ float fast_exp2(float x) {
#if __has_builtin(__builtin_amdgcn_exp2f)
    return __builtin_amdgcn_exp2f(x);
#else
    return exp2f(x);
#endif
}

// jax.nn.softplus(x) = max(x,0) + log1p(exp(-|x|))
__device__ __forceinline__ float softplus(float x) {
    return fmaxf(x, 0.0f) + log1pf(expf(-fabsf(x)));
}

// T arrives as a 1-element array of unknown encoding (python int scalar).
__device__ __forceinline__ float read_T(const void* p) {
    float f = *(const float*)p;
    if (f > 0.5f && f < 1.0e9f) return f;
    return (float)(*(const int*)p);
}

__global__ __launch_bounds__(256) void hawkes_pairs(
        const float* __restrict__ tp, const int* __restrict__ et,
        const float* __restrict__ la, const float* __restrict__ lb,
        float* __restrict__ partial, float* __restrict__ out) {
    const int ib = blockIdx.y, jb = blockIdx.x;
    if (jb > 2 * ib + 1) return;

    __shared__ float  nbl2_s[DT * DT];
    __shared__ float  lab_s[DT * DT];
    __shared__ float4 tile4[DT * R4];

    const int tid = threadIdx.x;
    if (tid < DT * DT) {
        float a = softplus(la[tid]);
        float b = softplus(lb[tid]);
        nbl2_s[tid] = -b * LOG2E;
        lab_s[tid]  = log2f(a * b);
    }
    __syncthreads();

    const int j0 = jb * JCH;
    if (tid < JCH) {
        const float tj = tp[j0 + tid];
        const int   ej = et[j0 + tid];
        float2* tile2 = (float2*)tile4;
#pragma unroll
        for (int r = 0; r < DT; ++r) {
            float P = nbl2_s[r * DT + ej];
            float L = fmaf(-P, tj, lab_s[r * DT + ej]);
            tile2[r * (2 * R4) + tid] = make_float2(P, L);
        }
    }
    __syncthreads();

    const int i = (ib << 8) + tid;
    const float ti = tp[i];
    const float4* __restrict__ row4 = &tile4[et[i] * R4];

    int n = i - j0;                       // strict j < i
    n = n < 0 ? 0 : (n > JCH ? JCH : n);

    float a0 = 0.0f, a1 = 0.0f, a2 = 0.0f, a3 = 0.0f;
    const int it = n >> 2;
    for (int k = 0; k < it; ++k) {
        float4 c0 = row4[2 * k];
        float4 c1 = row4[2 * k + 1];
        a0 += fast_exp2(fmaf(c0.x, ti, c0.y));
        a1 += fast_exp2(fmaf(c0.z, ti, c0.w));
        a2 += fast_exp2(fmaf(c1.x, ti, c1.y));
        a3 += fast_exp2(fmaf(c1.z, ti, c1.w));
    }
    const float2* row2 = (const float2*)row4;
    for (int j = it << 2; j < n; ++j) {
        float2 c = row2[j];
        a0 += fast_exp2(fmaf(c.x, ti, c.y));
    }
    partial[(jb << 13) + i] = (a0 + a1) + (a2 + a3);  // one writer per slot

    if (ib == 0 && jb == 0 && tid == 0) out[0] = 0.0f;
}

__global__ __launch_bounds__(256) void hawkes_finish(
        const float* __restrict__ tp, const int* __restrict__ et,
        const float* __restrict__ mu, const float* __restrict__ la,
        const float* __restrict__ lb, const void* __restrict__ Tp,
        const float* __restrict__ partial, float* __restrict__ out) {
    __shared__ float mu_s[DT];
    __shared__ float alpha_s[DT * DT];
    __shared__ float nbl2_s[DT * DT];

    const int tid = threadIdx.x;
    if (tid < DT * DT) {
        alpha_s[tid] = softplus(la[tid]);
        nbl2_s[tid]  = -softplus(lb[tid]) * LOG2E;
    }
    if (tid >= 128 && tid < 128 + DT) mu_s[tid - 128] = softplus(mu[tid - 128]);
    __syncthreads();

    const int b = blockIdx.x;
    const int i = (b << 8) + tid;
    const float Tf = read_T(Tp);

    float acc = 0.0f;
    for (int jb = 0; jb < 2 * b + 2; ++jb) acc += partial[(jb << 13) + i];

    const int e = et[i];
    float val = logf(mu_s[e] + acc);

    const float delta = Tf - tp[i];
#pragma unroll
    for (int d = 0; d < DT; ++d)
        val -= alpha_s[d * DT + e] * (1.0f - fast_exp2(nbl2_s[d * DT + e] * delta));

    if (i == 0) {
        float s = 0.0f;
#pragma unroll
        for (int d = 0; d < DT; ++d) s += mu_s[d];
        val -= s * Tf;   // -T * sum(mu_s)
    }

    // wave reduce (64 lanes) then cross-wave via LDS
    for (int o = 32; o > 0; o >>= 1) val += __shfl_down(val, o);
    __shared__ float wsum[4];
    const int lane = tid & 63, wv = tid >> 6;
    if (lane == 0) wsum[wv] = val;
    __syncthreads();
    if (tid == 0) atomicAdd(out, wsum[0] + wsum[1] + wsum[2] + wsum[3]);
}

extern "C" void kernel_launch(void* const* d_in, const int* in_sizes, int n_in,
                              void* d_out, int out_size, void* d_ws, size_t ws_size,
                              hipStream_t stream) {
    const float* tp = (const float*)d_in[0];
    const int*   et = (const int*)d_in[1];
    const float* mu = (const float*)d_in[2];
    const float* la = (const float*)d_in[3];
    const float* lb = (const float*)d_in[4];
    const void*  Tp = d_in[5];
    float* out = (float*)d_out;
    float* ws  = (float*)d_ws;

    dim3 grid(64, 32);
    hawkes_pairs<<<grid, 256, 0, stream>>>(tp, et, la, lb, ws, out);
    hawkes_finish<<<32, 256, 0, stream>>>(tp, et, mu, la, lb, Tp, ws, out);
}

// Round 7
// 81.696 us; speedup vs baseline: 1.1351x; 1.1351x over previous
//
#include <hip/hip_runtime.h>

// Multivariate Hawkes log-likelihood, N=8192, D=10.
// Pair term: ab*exp(-b*(ti-tj)) = exp2(P*ti + L), P = -b*log2e (per (e_i,e_j)),
// L = log2(a*b) - P*t_j. Per 256-wide j-tile we precompute (P,L) for all 10
// e_i rows, packed 2 pairs per float4 -> 1 ds_read_b128 per 4 pairs.
// Row stride 129 float4 (516 words, 516%32=4): 10 row bases spread over bank
// quads with worst-case 2-way aliasing (free per m136).
//
// Structure (best measured, R5) :
//   hawkes_pairs : grid(32,32) lower-tri (528 active); block (ib,jb) writes
//                  256 partial sums to partial[jb*8192+i] (single writer,
//                  poison-safe). Block (0,0) zeroes out[0] (stream order).
//   hawkes_finish: 32 blocks x 256 thr; log-intensity minus integral tail,
//                  block reduce, atomicAdd into out[0].
// Measured floor note: timed window is dominated by the harness's 268 MB
// d_ws re-poison (~40 us @ 85% HBM) + restore/graph overhead (~35 us);
// these kernels are ~5 us combined.

#define N_EV 8192
#define DT 10
#define LOG2E 1.4426950408889634f
#define R4 129   // row stride in float4 units (256 j = 128 float4 + 1 pad)

__device__ __forceinline__ float fast_exp2(float x) {
#if __has_builtin(__builtin_amdgcn_exp2f)
    return __builtin_amdgcn_exp2f(x);
#else
    return exp2f(x);
#endif
}

// jax.nn.softplus(x) = max(x,0) + log1p(exp(-|x|))
__device__ __forceinline__ float softplus(float x) {
    return fmaxf(x, 0.0f) + log1pf(expf(-fabsf(x)));
}

// T arrives as a 1-element array of unknown encoding (python int scalar).
__device__ __forceinline__ float read_T(const void* p) {
    float f = *(const float*)p;
    if (f > 0.5f && f < 1.0e9f) return f;
    return (float)(*(const int*)p);
}

__global__ __launch_bounds__(256) void hawkes_pairs(
        const float* __restrict__ tp, const int* __restrict__ et,
        const float* __restrict__ la, const float* __restrict__ lb,
        float* __restrict__ partial, float* __restrict__ out) {
    const int ib = blockIdx.y, jb = blockIdx.x;
    if (jb > ib) return;

    __shared__ float  nbl2_s[DT * DT];
    __shared__ float  lab_s[DT * DT];
    __shared__ float4 tile4[DT * R4];

    const int tid = threadIdx.x;
    if (tid < DT * DT) {
        float a = softplus(la[tid]);
        float b = softplus(lb[tid]);
        nbl2_s[tid] = -b * LOG2E;
        lab_s[tid]  = log2f(a * b);
    }
    __syncthreads();

    const int j0 = jb << 8;
    {
        const float tj = tp[j0 + tid];
        const int   ej = et[j0 + tid];
        float2* tile2 = (float2*)tile4;
#pragma unroll
        for (int r = 0; r < DT; ++r) {
            float P = nbl2_s[r * DT + ej];
            float L = fmaf(-P, tj, lab_s[r * DT + ej]);
            tile2[r * (2 * R4) + tid] = make_float2(P, L);
        }
    }
    __syncthreads();

    const int i = (ib << 8) + tid;
    const float ti = tp[i];
    const float4* __restrict__ row4 = &tile4[et[i] * R4];

    const int n = (ib == jb) ? tid : 256;   // strict j < i on the diagonal

    float a0 = 0.0f, a1 = 0.0f, a2 = 0.0f, a3 = 0.0f;
    const int it = n >> 2;
    for (int k = 0; k < it; ++k) {
        float4 c0 = row4[2 * k];
        float4 c1 = row4[2 * k + 1];
        a0 += fast_exp2(fmaf(c0.x, ti, c0.y));
        a1 += fast_exp2(fmaf(c0.z, ti, c0.w));
        a2 += fast_exp2(fmaf(c1.x, ti, c1.y));
        a3 += fast_exp2(fmaf(c1.z, ti, c1.w));
    }
    const float2* row2 = (const float2*)row4;
    for (int j = it << 2; j < n; ++j) {
        float2 c = row2[j];
        a0 += fast_exp2(fmaf(c.x, ti, c.y));
    }
    partial[(jb << 13) + i] = (a0 + a1) + (a2 + a3);  // one writer per slot

    if (ib == 0 && jb == 0 && tid == 0) out[0] = 0.0f;
}

__global__ __launch_bounds__(256) void hawkes_finish(
        const float* __restrict__ tp, const int* __restrict__ et,
        const float* __restrict__ mu, const float* __restrict__ la,
        const float* __restrict__ lb, const void* __restrict__ Tp,
        const float* __restrict__ partial, float* __restrict__ out) {
    __shared__ float mu_s[DT];
    __shared__ float alpha_s[DT * DT];
    __shared__ float nbl2_s[DT * DT];

    const int tid = threadIdx.x;
    if (tid < DT * DT) {
        alpha_s[tid] = softplus(la[tid]);
        nbl2_s[tid]  = -softplus(lb[tid]) * LOG2E;
    }
    if (tid >= 128 && tid < 128 + DT) mu_s[tid - 128] = softplus(mu[tid - 128]);
    __syncthreads();

    const int b = blockIdx.x;
    const int i = (b << 8) + tid;
    const float Tf = read_T(Tp);

    float acc = 0.0f;
    for (int jb = 0; jb <= b; ++jb) acc += partial[(jb << 13) + i];

    const int e = et[i];
    float val = logf(mu_s[e] + acc);

    const float delta = Tf - tp[i];
#pragma unroll
    for (int d = 0; d < DT; ++d)
        val -= alpha_s[d * DT + e] * (1.0f - fast_exp2(nbl2_s[d * DT + e] * delta));

    if (i == 0) {
        float s = 0.0f;
#pragma unroll
        for (int d = 0; d < DT; ++d) s += mu_s[d];
        val -= s * Tf;   // -T * sum(mu_s)
    }

    // wave reduce (64 lanes) then cross-wave via LDS
    for (int o = 32; o > 0; o >>= 1) val += __shfl_down(val, o);
    __shared__ float wsum[4];
    const int lane = tid & 63, wv = tid >> 6;
    if (lane == 0) wsum[wv] = val;
    __syncthreads();
    if (tid == 0) atomicAdd(out, wsum[0] + wsum[1] + wsum[2] + wsum[3]);
}

extern "C" void kernel_launch(void* const* d_in, const int* in_sizes, int n_in,
                              void* d_out, int out_size, void* d_ws, size_t ws_size,
                              hipStream_t stream) {
    const float* tp = (const float*)d_in[0];
    const int*   et = (const int*)d_in[1];
    const float* mu = (const float*)d_in[2];
    const float* la = (const float*)d_in[3];
    const float* lb = (const float*)d_in[4];
    const void*  Tp = d_in[5];
    float* out = (float*)d_out;
    float* ws  = (float*)d_ws;

    dim3 grid(32, 32);
    hawkes_pairs<<<grid, 256, 0, stream>>>(tp, et, la, lb, ws, out);
    hawkes_finish<<<32, 256, 0, stream>>>(tp, et, mu, la, lb, Tp, ws, out);
}

// Round 8
// 75.901 us; speedup vs baseline: 1.2218x; 1.0763x over previous
//
#include <hip/hip_runtime.h>

// Multivariate Hawkes log-likelihood, N=8192, D=10 — tile-factorized O(N·D).
//
// Times are sorted. For event i in tile ib, split Σ_{j<i}:
//   diagonal tile  : pairwise loop (avg 128 j), (P,L) trick:
//                    ab·exp(-b(ti-tj)) = exp2(P·ti + L), P=-b·log2e,
//                    L=log2(ab)-P·tj, staged per-row in LDS float4 pairs.
//   earlier tiles  : exp(-b(ti-tj)) = exp2(P(ti-tref_prev)) ·
//                    exp2(P(tref_prev-tref_k)) · exp2(P(tref_k-tj)),
//                    every factor in (0,1] (sorted times -> no overflow).
//     S_tile[k][r][d] = Σ_{j in k, e_j=d} exp2(P[r][d](tj-tref_k))  (kernel A)
//     per i: Σ_d ab[e_i,d]·exp2(P(ti-tref_prev))·Σ_k exp2(P(tref_prev-tref_k))·S_tile[k][e_i][d]
// Total exps ~1.3M vs 33.5M naive.
//
// Dispatches:
//   A hawkes_tilestats: 32 blocks x 256; LDS ds_add_f32 histogram -> S_tile
//                       (ws[0..3200)), block 0 zeroes out[0] (stream order).
//   C hawkes_finish   : 32 blocks x 256; per-(r,d) cross-tile scan (tid<100),
//                       diagonal (P,L) pairwise, log-intensity, integral
//                       tail, block reduce, atomicAdd out[0].
// Timed window is dominated by the harness's 268 MB d_ws re-poison (~40 us
// @ 85% HBM) + restore/graph overhead; these kernels are ~3-5 us.

#define N_EV 8192
#define DT 10
#define LOG2E 1.4426950408889634f
#define R4 129   // diagonal tile row stride in float4 (256 j = 128 f4 + pad)

__device__ __forceinline__ float fast_exp2(float x) {
#if __has_builtin(__builtin_amdgcn_exp2f)
    return __builtin_amdgcn_exp2f(x);
#else
    return exp2f(x);
#endif
}

// jax.nn.softplus(x) = max(x,0) + log1p(exp(-|x|))
__device__ __forceinline__ float softplus(float x) {
    return fmaxf(x, 0.0f) + log1pf(expf(-fabsf(x)));
}

// T arrives as a 1-element array of unknown encoding (python int scalar).
__device__ __forceinline__ float read_T(const void* p) {
    float f = *(const float*)p;
    if (f > 0.5f && f < 1.0e9f) return f;
    return (float)(*(const int*)p);
}

__global__ __launch_bounds__(256) void hawkes_tilestats(
        const float* __restrict__ tp, const int* __restrict__ et,
        const float* __restrict__ lb,
        float* __restrict__ S_tile, float* __restrict__ out) {
    __shared__ float nbl2_s[DT * DT];
    __shared__ float S_lds[DT * DT];
    const int k = blockIdx.x, tid = threadIdx.x;

    if (tid < DT * DT) {
        nbl2_s[tid] = -softplus(lb[tid]) * LOG2E;
        S_lds[tid] = 0.0f;
    }
    __syncthreads();

    const int j = (k << 8) + tid;
    const float dtr = tp[(k << 8) + 255] - tp[j];   // tref_k - tj >= 0
    const int ej = et[j];
#pragma unroll
    for (int r = 0; r < DT; ++r)
        atomicAdd(&S_lds[r * DT + ej], fast_exp2(nbl2_s[r * DT + ej] * dtr));
    __syncthreads();

    if (tid < DT * DT) S_tile[k * (DT * DT) + tid] = S_lds[tid];
    if (k == 0 && tid == 0) out[0] = 0.0f;          // finish atomicAdds later
}

__global__ __launch_bounds__(256) void hawkes_finish(
        const float* __restrict__ tp, const int* __restrict__ et,
        const float* __restrict__ mu, const float* __restrict__ la,
        const float* __restrict__ lb, const void* __restrict__ Tp,
        const float* __restrict__ S_tile, float* __restrict__ out) {
    __shared__ float  nbl2_s[DT * DT];
    __shared__ float  lab_s[DT * DT];
    __shared__ float  alpha_s[DT * DT];
    __shared__ float  cs[DT * DT];      // ab[r][d] * S_cum[r][d] for this block
    __shared__ float  mu_s[DT];
    __shared__ float  tref_s[32];
    __shared__ float4 tile4[DT * R4];   // diagonal (P,L) pairs

    const int ib = blockIdx.x, tid = threadIdx.x;

    float a = 0.0f, b = 0.0f;
    if (tid < DT * DT) {
        a = softplus(la[tid]);
        b = softplus(lb[tid]);
        nbl2_s[tid]  = -b * LOG2E;
        lab_s[tid]   = log2f(a * b);
        alpha_s[tid] = a;
    }
    if (tid < 32) tref_s[tid] = tp[(tid << 8) + 255];
    if (tid >= 128 && tid < 128 + DT) mu_s[tid - 128] = softplus(mu[tid - 128]);
    __syncthreads();

    // cross-tile scan: thread (r,d)=tid accumulates over earlier tiles
    if (tid < DT * DT) {
        const float P = nbl2_s[tid];
        const float trefp = tref_s[ib > 0 ? ib - 1 : 0];
        float s = 0.0f;
        for (int k = 0; k < ib; ++k)
            s += fast_exp2(P * (trefp - tref_s[k])) * S_tile[k * (DT * DT) + tid];
        cs[tid] = a * b * s;
    }

    // diagonal (P,L) staging (own tile)
    {
        const float tj = tp[(ib << 8) + tid];
        const int   ej = et[(ib << 8) + tid];
        float2* tile2 = (float2*)tile4;
#pragma unroll
        for (int r = 0; r < DT; ++r) {
            float P = nbl2_s[r * DT + ej];
            float L = fmaf(-P, tj, lab_s[r * DT + ej]);
            tile2[r * (2 * R4) + tid] = make_float2(P, L);
        }
    }
    __syncthreads();

    const int i = (ib << 8) + tid;
    const float ti = tp[i];
    const int e = et[i];
    const float Tf = read_T(Tp);

    // diagonal pairwise: strict j < i within the tile
    const float4* __restrict__ row4 = &tile4[e * R4];
    const int n = tid;
    float a0 = 0.0f, a1 = 0.0f, a2 = 0.0f, a3 = 0.0f;
    const int it = n >> 2;
    for (int kk = 0; kk < it; ++kk) {
        float4 c0 = row4[2 * kk];
        float4 c1 = row4[2 * kk + 1];
        a0 += fast_exp2(fmaf(c0.x, ti, c0.y));
        a1 += fast_exp2(fmaf(c0.z, ti, c0.w));
        a2 += fast_exp2(fmaf(c1.x, ti, c1.y));
        a3 += fast_exp2(fmaf(c1.z, ti, c1.w));
    }
    const float2* row2 = (const float2*)row4;
    for (int j = it << 2; j < n; ++j) {
        float2 c = row2[j];
        a0 += fast_exp2(fmaf(c.x, ti, c.y));
    }
    float acc = (a0 + a1) + (a2 + a3);

    // cross-tile contribution
    if (ib > 0) {
        const float dtp = ti - tref_s[ib - 1];   // >= 0
#pragma unroll
        for (int d = 0; d < DT; ++d)
            acc += cs[e * DT + d] * fast_exp2(nbl2_s[e * DT + d] * dtp);
    }

    float val = logf(mu_s[e] + acc);

    // integral tail
    const float delta = Tf - ti;
#pragma unroll
    for (int d = 0; d < DT; ++d)
        val -= alpha_s[d * DT + e] * (1.0f - fast_exp2(nbl2_s[d * DT + e] * delta));

    if (i == 0) {
        float s = 0.0f;
#pragma unroll
        for (int d = 0; d < DT; ++d) s += mu_s[d];
        val -= s * Tf;   // -T * sum(mu_s)
    }

    // wave reduce (64 lanes) then cross-wave via LDS
    for (int o = 32; o > 0; o >>= 1) val += __shfl_down(val, o);
    __shared__ float wsum[4];
    const int lane = tid & 63, wv = tid >> 6;
    if (lane == 0) wsum[wv] = val;
    __syncthreads();
    if (tid == 0) atomicAdd(out, wsum[0] + wsum[1] + wsum[2] + wsum[3]);
}

extern "C" void kernel_launch(void* const* d_in, const int* in_sizes, int n_in,
                              void* d_out, int out_size, void* d_ws, size_t ws_size,
                              hipStream_t stream) {
    const float* tp = (const float*)d_in[0];
    const int*   et = (const int*)d_in[1];
    const float* mu = (const float*)d_in[2];
    const float* la = (const float*)d_in[3];
    const float* lb = (const float*)d_in[4];
    const void*  Tp = d_in[5];
    float* out = (float*)d_out;
    float* ws  = (float*)d_ws;

    hawkes_tilestats<<<32, 256, 0, stream>>>(tp, et, lb, ws, out);
    hawkes_finish<<<32, 256, 0, stream>>>(tp, et, mu, la, lb, Tp, ws, out);
}